// Round 1
// baseline (732.801 us; speedup 1.0000x reference)
//
#include <hip/hip_runtime.h>

typedef float v4 __attribute__((ext_vector_type(4)));
typedef float v2 __attribute__((ext_vector_type(2)));

#define NEGV 1000000000000.0f
#define SEQ 512
#define NB 16
#define NL 20
#define LOGITS_ELEMS (16 * 20 * 512 * 512)   // 83,886,080

// ---------------------------------------------------------------------------
// Kernel 1: out = x @ [w1 | w2] + [b1 | b2], then RoPE the w1-half into
// qw,kw (deinterleaved) and store the w2-half transposed/2 as dense[b][40][S].
// BM=32 rows, BN=64 cols per block; jb=0,1 -> w1 cols, jb=2 -> w2 cols.
// ---------------------------------------------------------------------------
__global__ __launch_bounds__(256)
void prep_kernel(const float* __restrict__ x, const float* __restrict__ w1,
                 const float* __restrict__ b1, const float* __restrict__ w2,
                 const float* __restrict__ b2,
                 float* __restrict__ qw, float* __restrict__ kw,
                 float* __restrict__ dense)
{
    __shared__ float xs[32][36];    // pad 36: 16B-aligned rows, conflict-free
    __shared__ float wsm[32][64];   // [k][n]

    const int tid = threadIdx.x;
    const int jb = blockIdx.x;           // 0..2
    const int m0 = blockIdx.y * 32;      // global row block
    const int j0 = jb * 64;

    const int tx = tid & 15;             // n/4
    const int ty = tid >> 4;             // 0..15, rows ty and ty+16

    const int sxm = tid >> 3;            // 0..31
    const int sxk = (tid & 7) * 4;       // 0..28
    const int swk = tid >> 3;            // 0..31 (k)
    const int swn = (tid & 7) * 8;       // 0..56 (n)

    float acc0[4] = {0.f, 0.f, 0.f, 0.f};
    float acc1[4] = {0.f, 0.f, 0.f, 0.f};

    for (int k0 = 0; k0 < 768; k0 += 32) {
        v4 xa = *(const v4*)&x[(size_t)(m0 + sxm) * 768 + k0 + sxk];
        v4 wa, wb;
        if (jb < 2) {
            wa = *(const v4*)&w1[(size_t)(k0 + swk) * 128 + j0 + swn];
            wb = *(const v4*)&w1[(size_t)(k0 + swk) * 128 + j0 + swn + 4];
        } else if (swn < 40) {
            wa = *(const v4*)&w2[(size_t)(k0 + swk) * 40 + swn];
            wb = *(const v4*)&w2[(size_t)(k0 + swk) * 40 + swn + 4];
        } else {
            wa = 0.0f; wb = 0.0f;
        }
        __syncthreads();
        *(v4*)&xs[sxm][sxk] = xa;
        *(v4*)&wsm[swk][swn] = wa;
        *(v4*)&wsm[swk][swn + 4] = wb;
        __syncthreads();
#pragma unroll
        for (int k = 0; k < 32; k += 4) {
            v4 a0 = *(const v4*)&xs[ty][k];
            v4 a1 = *(const v4*)&xs[ty + 16][k];
            v4 bv0 = *(const v4*)&wsm[k + 0][tx * 4];
            v4 bv1 = *(const v4*)&wsm[k + 1][tx * 4];
            v4 bv2 = *(const v4*)&wsm[k + 2][tx * 4];
            v4 bv3 = *(const v4*)&wsm[k + 3][tx * 4];
#pragma unroll
            for (int j = 0; j < 4; ++j) {
                acc0[j] += a0[0] * bv0[j] + a0[1] * bv1[j] + a0[2] * bv2[j] + a0[3] * bv3[j];
                acc1[j] += a1[0] * bv0[j] + a1[1] * bv1[j] + a1[2] * bv2[j] + a1[3] * bv3[j];
            }
        }
    }

    if (jb < 2) {
        // cols j = j0+4tx .. +3 = {q[2p], k[2p], q[2p+1], k[2p+1]}, p = j0/4+tx
        const int p = (j0 >> 2) + tx;    // 0..31 rope pair index
        const float fr = __powf(10000.0f, (float)(-2 * p) / 64.0f);
        v4 bb = *(const v4*)&b1[j0 + tx * 4];
#pragma unroll
        for (int i = 0; i < 2; ++i) {
            const float* acc = (i == 0) ? acc0 : acc1;
            const int mrow = m0 + ty + 16 * i;       // global row = b*512+s
            const int s = mrow & 511;
            float ang = (float)s * fr;
            float sn = sinf(ang), cs = cosf(ang);
            float q0 = acc[0] + bb[0];
            float k0v = acc[1] + bb[1];
            float q1 = acc[2] + bb[2];
            float k1v = acc[3] + bb[3];
            v2 qo, ko;
            qo[0] = q0 * cs - q1 * sn;  qo[1] = q1 * cs + q0 * sn;
            ko[0] = k0v * cs - k1v * sn; ko[1] = k1v * cs + k0v * sn;
            *(v2*)&qw[(size_t)mrow * 64 + 2 * p] = qo;
            *(v2*)&kw[(size_t)mrow * 64 + 2 * p] = ko;
        }
    } else if (tx < 10) {
        // dense cols jd = 4tx..4tx+3 (0..39), store dense[b][jd][s] = (v+b2)/2
        v4 bb = *(const v4*)&b2[tx * 4];
#pragma unroll
        for (int i = 0; i < 2; ++i) {
            const float* acc = (i == 0) ? acc0 : acc1;
            const int mrow = m0 + ty + 16 * i;
            const int bi = mrow >> 9;
            const int s = mrow & 511;
#pragma unroll
            for (int j = 0; j < 4; ++j) {
                dense[(size_t)(bi * 40 + tx * 4 + j) * 512 + s] = (acc[j] + bb[j]) * 0.5f;
            }
        }
    }
}

// ---------------------------------------------------------------------------
// Kernel 2: per (b, m-tile 32, n-tile 64): qk = qw·kw^T / 8, then for l=0..19:
//   logits[b,l,m,n] = qk + dense[b,2l,n] + dense[b,2l+1,m], masked + tril,
//   probs = sigmoid(logits). Coalesced float4 stores of both outputs.
// ---------------------------------------------------------------------------
__global__ __launch_bounds__(256)
void fused_kernel(const float* __restrict__ qw, const float* __restrict__ kw,
                  const float* __restrict__ dense, const int* __restrict__ mask,
                  float* __restrict__ outL, float* __restrict__ outP)
{
    __shared__ float qwL[32][68];   // [m][k], pad 68 keeps 16B alignment
    __shared__ float kwT[64][64];   // [k][n]
    __shared__ float dEs[20][64];   // dense even rows over n-tile
    __shared__ float dOs[20][32];   // dense odd rows over m-tile
    __shared__ float mMs[32];
    __shared__ float mNs[64];

    const int tid = threadIdx.x;
    const int n0 = blockIdx.x * 64;
    const int m0 = blockIdx.y * 32;
    const int b  = blockIdx.z;

    // stage qw tile (32x64)
    {
        const int m = tid >> 3, kk = (tid & 7) * 8;
        v4 a = *(const v4*)&qw[(size_t)(b * SEQ + m0 + m) * 64 + kk];
        v4 c = *(const v4*)&qw[(size_t)(b * SEQ + m0 + m) * 64 + kk + 4];
        *(v4*)&qwL[m][kk] = a;
        *(v4*)&qwL[m][kk + 4] = c;
    }
    // stage kw tile transposed (64 rows n, 64 k) -> kwT[k][n]
    {
        const int n = tid >> 2, kk = (tid & 3) * 16;
#pragma unroll
        for (int t = 0; t < 4; ++t) {
            v4 a = *(const v4*)&kw[(size_t)(b * SEQ + n0 + n) * 64 + kk + 4 * t];
            kwT[kk + 4 * t + 0][n] = a[0];
            kwT[kk + 4 * t + 1][n] = a[1];
            kwT[kk + 4 * t + 2][n] = a[2];
            kwT[kk + 4 * t + 3][n] = a[3];
        }
    }
    // stage dense even rows (20 x 64)
#pragma unroll
    for (int t = 0; t < 5; ++t) {
        int flat = t * 256 + tid;
        int l = flat >> 6, n = flat & 63;
        dEs[l][n] = dense[(size_t)(b * 40 + 2 * l) * 512 + n0 + n];
    }
    // stage dense odd rows (20 x 32)
#pragma unroll
    for (int t = 0; t < 3; ++t) {
        int flat = t * 256 + tid;
        if (flat < 640) {
            int l = flat >> 5, m = flat & 31;
            dOs[l][m] = dense[(size_t)(b * 40 + 2 * l + 1) * 512 + m0 + m];
        }
    }
    if (tid < 64) mNs[tid] = (float)mask[b * SEQ + n0 + tid];
    else if (tid < 96) mMs[tid - 64] = (float)mask[b * SEQ + m0 + (tid - 64)];
    __syncthreads();

    const int tx = tid & 15;   // n/4
    const int r  = tid >> 4;   // rows r, r+16

    float acc0[4] = {0.f, 0.f, 0.f, 0.f};
    float acc1[4] = {0.f, 0.f, 0.f, 0.f};
#pragma unroll
    for (int k = 0; k < 64; k += 4) {
        v4 a0 = *(const v4*)&qwL[r][k];
        v4 a1 = *(const v4*)&qwL[r + 16][k];
        v4 bv0 = *(const v4*)&kwT[k + 0][tx * 4];
        v4 bv1 = *(const v4*)&kwT[k + 1][tx * 4];
        v4 bv2 = *(const v4*)&kwT[k + 2][tx * 4];
        v4 bv3 = *(const v4*)&kwT[k + 3][tx * 4];
#pragma unroll
        for (int j = 0; j < 4; ++j) {
            acc0[j] += a0[0] * bv0[j] + a0[1] * bv1[j] + a0[2] * bv2[j] + a0[3] * bv3[j];
            acc1[j] += a1[0] * bv0[j] + a1[1] * bv1[j] + a1[2] * bv2[j] + a1[3] * bv3[j];
        }
    }

    const float mM0 = mMs[r], mM1 = mMs[r + 16];
    const float cM0 = -NEGV * (1.0f - mM0);
    const float cM1 = -NEGV * (1.0f - mM1);
    v4 mNv = *(const v4*)&mNs[tx * 4];
    v4 cN;
#pragma unroll
    for (int j = 0; j < 4; ++j) cN[j] = -NEGV * (1.0f - mNv[j]);
    const int gm0 = m0 + r, gm1 = m0 + r + 16;
#pragma unroll
    for (int j = 0; j < 4; ++j) { acc0[j] *= 0.125f; acc1[j] *= 0.125f; }

    for (int l = 0; l < NL; ++l) {
        v4 de = *(const v4*)&dEs[l][tx * 4];
        float do0 = dOs[l][r], do1 = dOs[l][r + 16];
        v4 lv0, lv1, pv0, pv1;
#pragma unroll
        for (int j = 0; j < 4; ++j) {
            const int gn = n0 + tx * 4 + j;
            float v = acc0[j] + de[j] + do0;
            v = v * mM0 + cM0;          // == v*m1 - NEG*(1-m1), exact for m=1
            v = v * mNv[j] + cN[j];
            if (gm0 > gn) v -= NEGV;    // strict lower triangle
            lv0[j] = v;
            pv0[j] = __builtin_amdgcn_rcpf(1.0f + __expf(-v));
            float u = acc1[j] + de[j] + do1;
            u = u * mM1 + cM1;
            u = u * mNv[j] + cN[j];
            if (gm1 > gn) u -= NEGV;
            lv1[j] = u;
            pv1[j] = __builtin_amdgcn_rcpf(1.0f + __expf(-u));
        }
        const size_t base0 = ((size_t)(b * NL + l) * SEQ + gm0) * SEQ + n0 + tx * 4;
        const size_t base1 = ((size_t)(b * NL + l) * SEQ + gm1) * SEQ + n0 + tx * 4;
        *(v4*)&outL[base0] = lv0;
        *(v4*)&outL[base1] = lv1;
        *(v4*)&outP[base0] = pv0;
        *(v4*)&outP[base1] = pv1;
    }
}

extern "C" void kernel_launch(void* const* d_in, const int* in_sizes, int n_in,
                              void* d_out, int out_size, void* d_ws, size_t ws_size,
                              hipStream_t stream) {
    (void)in_sizes; (void)n_in; (void)out_size; (void)ws_size;
    const float* x    = (const float*)d_in[0];
    const int*   mask = (const int*)d_in[1];
    const float* w1   = (const float*)d_in[2];
    const float* b1   = (const float*)d_in[3];
    const float* w2   = (const float*)d_in[4];
    const float* b2   = (const float*)d_in[5];

    float* ws = (float*)d_ws;
    float* qw    = ws;                       // 16*512*64  = 524288 floats
    float* kw    = ws + 524288;              // 524288 floats
    float* dense = ws + 1048576;             // 16*40*512  = 327680 floats

    float* outL = (float*)d_out;
    float* outP = outL + (size_t)LOGITS_ELEMS;

    prep_kernel<<<dim3(3, 256), 256, 0, stream>>>(x, w1, b1, w2, b2, qw, kw, dense);
    fused_kernel<<<dim3(8, 16, 16), 256, 0, stream>>>(qw, kw, dense, mask, outL, outP);
}